// Round 1
// baseline (54.910 us; speedup 1.0000x reference)
//
#include <hip/hip_runtime.h>

// GCNAggregator: B=4096 rows, K=32 neighbor indices into U=16384 node tables
// of D=256 f32. Set-semantics mask, symmetric GCN norm:
//   out_feats[b,:]  = sum_{unique u in row b} feat[u,:]  / (sqrt(rowcnt_b)*sqrt(colcnt_u))
//   out_noise[b,:]  = same with noise table
// d_out = [to_feats (B*D) | to_noise (B*D)] f32.

#define B_ 4096
#define K_ 32
#define U_ 16384
#define D_ 256

// Pass 1: per-row dedup (wave-local, lanes 0..31 hold the 32 indices),
// atomicAdd unique (b,u) into colcnt[u].
__global__ __launch_bounds__(256) void gcn_colcount(const int* __restrict__ idx,
                                                    int* __restrict__ colcnt) {
    const int wave = (blockIdx.x * blockDim.x + threadIdx.x) >> 6;
    const int lane = threadIdx.x & 63;
    if (wave >= B_) return;

    const int kk = lane & 31;                  // lanes 32..63 mirror 0..31
    const int u = idx[wave * K_ + kk];

    bool dup = false;
    #pragma unroll
    for (int j = 0; j < K_; ++j) {
        const int uj = __shfl(u, j);
        if (j < kk && uj == u) dup = true;     // first occurrence wins
    }
    if (lane < 32 && !dup) atomicAdd(&colcnt[u], 1);
}

// Pass 2: one wave per row. Recompute dedup + rowcnt wave-locally, read
// colcnt, form per-k weight, then gather-accumulate both tables.
// Lane L owns output dims [4L, 4L+4) as float4.
__global__ __launch_bounds__(256) void gcn_gather(const int* __restrict__ idx,
                                                  const float4* __restrict__ feat,
                                                  const float4* __restrict__ noise,
                                                  const int* __restrict__ colcnt,
                                                  float4* __restrict__ out) {
    const int wavesPerBlock = blockDim.x >> 6;
    const int row = blockIdx.x * wavesPerBlock + (threadIdx.x >> 6);
    const int lane = threadIdx.x & 63;
    if (row >= B_) return;

    const int kk = lane & 31;
    const int u = idx[row * K_ + kk];

    bool dup = false;
    #pragma unroll
    for (int j = 0; j < K_; ++j) {
        const int uj = __shfl(u, j);
        if (j < kk && uj == u) dup = true;
    }
    // rowcnt = #unique in this row (count lanes 0..31 only; upper half mirrors)
    const unsigned long long uniq = __ballot(!dup) & 0xFFFFFFFFull;
    const int rowcnt = __popcll(uniq);

    // weight for slot kk; duplicates contribute 0. colcnt[u] >= 1 for any
    // referenced u, so no div-by-zero.
    float w = 0.0f;
    if (!dup) w = rsqrtf((float)(rowcnt * colcnt[u]));

    float4 accf = make_float4(0.f, 0.f, 0.f, 0.f);
    float4 accn = make_float4(0.f, 0.f, 0.f, 0.f);

    #pragma unroll
    for (int k = 0; k < K_; ++k) {
        // compile-time lane index -> v_readlane -> SGPR broadcast
        const int   uk = __builtin_amdgcn_readlane(u, k);
        const float wk = __uint_as_float(
            (unsigned)__builtin_amdgcn_readlane((int)__float_as_uint(w), k));

        const float4 vf = feat[uk * (D_ / 4) + lane];
        const float4 vn = noise[uk * (D_ / 4) + lane];
        accf.x = fmaf(wk, vf.x, accf.x);
        accf.y = fmaf(wk, vf.y, accf.y);
        accf.z = fmaf(wk, vf.z, accf.z);
        accf.w = fmaf(wk, vf.w, accf.w);
        accn.x = fmaf(wk, vn.x, accn.x);
        accn.y = fmaf(wk, vn.y, accn.y);
        accn.z = fmaf(wk, vn.z, accn.z);
        accn.w = fmaf(wk, vn.w, accn.w);
    }

    out[row * (D_ / 4) + lane] = accf;                 // to_feats
    out[(B_ + row) * (D_ / 4) + lane] = accn;          // to_noise_feats
}

extern "C" void kernel_launch(void* const* d_in, const int* in_sizes, int n_in,
                              void* d_out, int out_size, void* d_ws, size_t ws_size,
                              hipStream_t stream) {
    const int*    idx   = (const int*)d_in[0];        // [B,K] int32
    const float4* feat  = (const float4*)d_in[1];     // [U,D] f32
    const float4* noise = (const float4*)d_in[2];     // [U,D] f32
    float4*       out   = (float4*)d_out;             // [2*B, D] f32
    int*          colcnt = (int*)d_ws;                // U ints

    // zero column counts every call (deterministic; ws is not re-poisoned)
    hipMemsetAsync(colcnt, 0, U_ * sizeof(int), stream);

    // 4 waves (rows) per 256-thread block
    const int blocks = B_ / 4;
    gcn_colcount<<<blocks, 256, 0, stream>>>(idx, colcnt);
    gcn_gather<<<blocks, 256, 0, stream>>>(idx, feat, noise, colcnt, out);
}

// Round 2
// 53.825 us; speedup vs baseline: 1.0202x; 1.0202x over previous
//
#include <hip/hip_runtime.h>

// GCNAggregator: B=4096 rows, K=32 neighbor indices into U=16384 node tables
// of D=256 f32. Set-semantics mask, symmetric GCN norm:
//   out_feats[b,:]  = sum_{unique u in row b} feat[u,:]  / (sqrt(rowcnt_b)*sqrt(colcnt_u))
//   out_noise[b,:]  = same with noise table
// d_out = [to_feats (B*D) | to_noise (B*D)] f32.

#define B_ 4096
#define K_ 32
#define U_ 16384
#define D_ 256

// Pass 0: zero colcnt ourselves — hipMemsetAsync's fillBufferAligned showed
// up at 43 us in the profile; a plain 64-block store kernel is ~1-2 us.
__global__ __launch_bounds__(256) void gcn_zero(int* __restrict__ colcnt) {
    colcnt[blockIdx.x * 256 + threadIdx.x] = 0;
}

// Pass 1: per-row dedup (wave-local, lanes 0..31 hold the 32 indices),
// atomicAdd unique (b,u) into colcnt[u].
__global__ __launch_bounds__(256) void gcn_colcount(const int* __restrict__ idx,
                                                    int* __restrict__ colcnt) {
    const int wave = (blockIdx.x * blockDim.x + threadIdx.x) >> 6;
    const int lane = threadIdx.x & 63;
    if (wave >= B_) return;

    const int kk = lane & 31;                  // lanes 32..63 mirror 0..31
    const int u = idx[wave * K_ + kk];

    bool dup = false;
    #pragma unroll
    for (int j = 0; j < K_; ++j) {
        const int uj = __shfl(u, j);
        if (j < kk && uj == u) dup = true;     // first occurrence wins
    }
    if (lane < 32 && !dup) atomicAdd(&colcnt[u], 1);
}

// Pass 2: one wave per row. Recompute dedup + rowcnt wave-locally, read
// colcnt, form per-k weight, then gather-accumulate both tables.
// Lane L owns output dims [4L, 4L+4) as float4.
__global__ __launch_bounds__(256) void gcn_gather(const int* __restrict__ idx,
                                                  const float4* __restrict__ feat,
                                                  const float4* __restrict__ noise,
                                                  const int* __restrict__ colcnt,
                                                  float4* __restrict__ out) {
    const int wavesPerBlock = blockDim.x >> 6;
    const int row = blockIdx.x * wavesPerBlock + (threadIdx.x >> 6);
    const int lane = threadIdx.x & 63;
    if (row >= B_) return;

    const int kk = lane & 31;
    const int u = idx[row * K_ + kk];

    bool dup = false;
    #pragma unroll
    for (int j = 0; j < K_; ++j) {
        const int uj = __shfl(u, j);
        if (j < kk && uj == u) dup = true;
    }
    // rowcnt = #unique in this row (count lanes 0..31 only; upper half mirrors)
    const unsigned long long uniq = __ballot(!dup) & 0xFFFFFFFFull;
    const int rowcnt = __popcll(uniq);

    // weight for slot kk; duplicates contribute 0. colcnt[u] >= 1 for any
    // referenced u, so no div-by-zero.
    float w = 0.0f;
    if (!dup) w = rsqrtf((float)(rowcnt * colcnt[u]));

    float4 accf = make_float4(0.f, 0.f, 0.f, 0.f);
    float4 accn = make_float4(0.f, 0.f, 0.f, 0.f);

    #pragma unroll
    for (int k = 0; k < K_; ++k) {
        // compile-time lane index -> v_readlane -> SGPR broadcast; gather
        // address becomes SGPR-base + (lane*16) voffset.
        const int   uk = __builtin_amdgcn_readlane(u, k);
        const float wk = __uint_as_float(
            (unsigned)__builtin_amdgcn_readlane((int)__float_as_uint(w), k));

        const float4 vf = feat[uk * (D_ / 4) + lane];
        const float4 vn = noise[uk * (D_ / 4) + lane];
        accf.x = fmaf(wk, vf.x, accf.x);
        accf.y = fmaf(wk, vf.y, accf.y);
        accf.z = fmaf(wk, vf.z, accf.z);
        accf.w = fmaf(wk, vf.w, accf.w);
        accn.x = fmaf(wk, vn.x, accn.x);
        accn.y = fmaf(wk, vn.y, accn.y);
        accn.z = fmaf(wk, vn.z, accn.z);
        accn.w = fmaf(wk, vn.w, accn.w);
    }

    out[row * (D_ / 4) + lane] = accf;                 // to_feats
    out[(B_ + row) * (D_ / 4) + lane] = accn;          // to_noise_feats
}

extern "C" void kernel_launch(void* const* d_in, const int* in_sizes, int n_in,
                              void* d_out, int out_size, void* d_ws, size_t ws_size,
                              hipStream_t stream) {
    const int*    idx   = (const int*)d_in[0];        // [B,K] int32
    const float4* feat  = (const float4*)d_in[1];     // [U,D] f32
    const float4* noise = (const float4*)d_in[2];     // [U,D] f32
    float4*       out   = (float4*)d_out;             // [2*B, D] f32
    int*          colcnt = (int*)d_ws;                // U ints

    // zero column counts every call (deterministic; ws is not re-poisoned)
    gcn_zero<<<U_ / 256, 256, 0, stream>>>(colcnt);

    gcn_colcount<<<B_ / 4, 256, 0, stream>>>(idx, colcnt);
    gcn_gather<<<B_ / 4, 256, 0, stream>>>(idx, feat, noise, colcnt, out);
}